// Round 1
// baseline (637.265 us; speedup 1.0000x reference)
//
#include <hip/hip_runtime.h>
#include <stdint.h>

// ---------------------------------------------------------------------------
// MLA forward on MI355X. Round 0: correctness-first bf16-MFMA pipeline.
//   B=2 S=2048 D=2048 H=16 NOPE=128 ROPE=64 VD=128 QKD=192 QR=1536 KR=512
// Pipeline:
//   cvt x,W -> bf16 | G1 qdown=x@Wqd^T | rms q | G2 q=qn@Wqu^T
//   G3 kv=x@Wkvd^T(pad N 576->640) | rms ckv | G4 kvup=ckvn@Wkvu^T
//   prep_q (rope+scale, repack BHS192) | prep_k | prep_v (transpose V)
//   flash attn (64 q-rows/block, KT=32) | G5 out=o@Wo^T+bo
// ---------------------------------------------------------------------------

typedef short bf16x8 __attribute__((ext_vector_type(8)));
typedef float f32x4  __attribute__((ext_vector_type(4)));

#define RMS_EPS 1.1920929e-07f

__device__ __forceinline__ unsigned short f2b(float f) {
  union { float f; uint32_t u; } c; c.f = f;
  uint32_t u = c.u;
  return (unsigned short)((u + 0x7FFFu + ((u >> 16) & 1u)) >> 16);
}

// ---------------- fp32 -> bf16 conversion ----------------
__global__ void f2bf_kernel(const float* __restrict__ in, short* __restrict__ out, int n4) {
  int i = blockIdx.x * 256 + threadIdx.x;
  if (i >= n4) return;
  float4 v = ((const float4*)in)[i];
  union { ushort4 s; uint2 u; } o;
  o.s.x = f2b(v.x); o.s.y = f2b(v.y); o.s.z = f2b(v.z); o.s.w = f2b(v.w);
  ((uint2*)out)[i] = o.u;
}

// pads rows [src_rows, n4/cols4) with zeros (Wkv_down 576 -> 640 rows)
__global__ void f2bf_pad_kernel(const float* __restrict__ in, short* __restrict__ out,
                                int n4, int cols4, int src_rows) {
  int i = blockIdx.x * 256 + threadIdx.x;
  if (i >= n4) return;
  int row = i / cols4;
  ushort4 s = {0, 0, 0, 0};
  if (row < src_rows) {
    float4 v = ((const float4*)in)[i];
    s.x = f2b(v.x); s.y = f2b(v.y); s.z = f2b(v.z); s.w = f2b(v.w);
  }
  union { ushort4 ss; uint2 u; } o; o.ss = s;
  ((uint2*)out)[i] = o.u;
}

// ---------------- GEMM: C[M,N]f32 = A[M,K]bf16 @ Bt[N,K]bf16^T (+bias) -------
// 128x128 tile, 4 waves (2x2), each wave 64x64 via 4x4 16x16x32 MFMA frags.
__global__ __launch_bounds__(256) void gemm_bt_kernel(
    const short* __restrict__ A, const short* __restrict__ Bt,
    float* __restrict__ C, const float* __restrict__ bias,
    int K, int ldc) {
  __shared__ __align__(16) short As[128 * 32];
  __shared__ __align__(16) short Bs[128 * 32];
  int row0 = blockIdx.y * 128, col0 = blockIdx.x * 128;
  int t = threadIdx.x, lane = t & 63, w = t >> 6;
  int wm = w >> 1, wn = w & 1;
  int l15 = lane & 15, l4 = lane >> 4;
  f32x4 acc[4][4] = {};

  int r_a = t >> 2;            // staging row 0..63 (+64 on 2nd chunk)
  int c8  = (t & 3) * 8;       // staging col chunk
  const short* Ap = A  + (size_t)(row0 + r_a) * K + c8;
  const short* Bp = Bt + (size_t)(col0 + r_a) * K + c8;

  for (int kt = 0; kt < K; kt += 32) {
    bf16x8 a0 = *(const bf16x8*)(Ap + kt);
    bf16x8 a1 = *(const bf16x8*)(Ap + (size_t)64 * K + kt);
    bf16x8 b0 = *(const bf16x8*)(Bp + kt);
    bf16x8 b1 = *(const bf16x8*)(Bp + (size_t)64 * K + kt);
    *(bf16x8*)(As + r_a * 32 + c8) = a0;
    *(bf16x8*)(As + (r_a + 64) * 32 + c8) = a1;
    *(bf16x8*)(Bs + r_a * 32 + c8) = b0;
    *(bf16x8*)(Bs + (r_a + 64) * 32 + c8) = b1;
    __syncthreads();
    bf16x8 af[4], bfr[4];
#pragma unroll
    for (int i = 0; i < 4; ++i) {
      af[i]  = *(const bf16x8*)(As + (wm * 64 + i * 16 + l15) * 32 + l4 * 8);
      bfr[i] = *(const bf16x8*)(Bs + (wn * 64 + i * 16 + l15) * 32 + l4 * 8);
    }
#pragma unroll
    for (int i = 0; i < 4; ++i)
#pragma unroll
      for (int j = 0; j < 4; ++j)
        acc[i][j] = __builtin_amdgcn_mfma_f32_16x16x32_bf16(af[i], bfr[j], acc[i][j], 0, 0, 0);
    __syncthreads();
  }
#pragma unroll
  for (int j = 0; j < 4; ++j) {
    int col = col0 + wn * 64 + j * 16 + l15;
    float bv = bias ? bias[col] : 0.0f;
#pragma unroll
    for (int i = 0; i < 4; ++i) {
      int row = row0 + wm * 64 + i * 16 + l4 * 4;
      float* dst = C + (size_t)row * ldc + col;
#pragma unroll
      for (int r = 0; r < 4; ++r) dst[(size_t)r * ldc] = acc[i][j][r] + bv;
    }
  }
}

// ---------------- RMSNorm (fp32 in, bf16 out) ----------------
__global__ __launch_bounds__(256) void rmsnorm_kernel(
    const float* __restrict__ in, const float* __restrict__ wgt,
    short* __restrict__ out, int W, int ld_in) {
  int row = blockIdx.x, t = threadIdx.x;
  const float* x = in + (size_t)row * ld_in;
  float ss = 0.f;
  for (int i = t; i < W; i += 256) { float v = x[i]; ss += v * v; }
#pragma unroll
  for (int off = 32; off > 0; off >>= 1) ss += __shfl_down(ss, off);
  __shared__ float red[4];
  if ((t & 63) == 0) red[t >> 6] = ss;
  __syncthreads();
  ss = red[0] + red[1] + red[2] + red[3];
  float rs = rsqrtf(ss / (float)W + RMS_EPS);
  for (int i = t; i < W; i += 256)
    out[(size_t)row * W + i] = (short)f2b(x[i] * rs * wgt[i]);
}

// ---------------- prep_q: rope + scale, (B,S,H,192)f32 -> (B,H,S,192)bf16 ----
__global__ void prep_q_kernel(const float* __restrict__ q, const float* __restrict__ fc,
                              const float* __restrict__ fs, short* __restrict__ qb, int n) {
  int idx = blockIdx.x * 256 + threadIdx.x;
  if (idx >= n) return;
  int i2 = idx % 96; int tmp = idx / 96;
  int h = tmp & 15; tmp >>= 4;
  int s = tmp & 2047; int b = tmp >> 11;
  const float* row = q + ((size_t)(b * 2048 + s)) * 3072 + h * 192;
  const float scale = 0.07216878364870323f;  // 1/sqrt(192)
  int d0 = 2 * i2;
  float v0, v1;
  if (d0 < 128) { v0 = row[d0]; v1 = row[d0 + 1]; }
  else {
    int i = i2 - 64;
    float c = fc[s * 32 + i], sn = fs[s * 32 + i];
    float x0 = row[d0], x1 = row[d0 + 1];
    v0 = x0 * c - x1 * sn; v1 = x0 * sn + x1 * c;
  }
  v0 *= scale; v1 *= scale;
  uint32_t pk = (uint32_t)f2b(v0) | ((uint32_t)f2b(v1) << 16);
  *(uint32_t*)(qb + (((size_t)(b * 16 + h) * 2048 + s) * 192 + d0)) = pk;
}

// ---------------- prep_k: k_nope + broadcast roped k_rope -> (B,H,S,192)bf16 --
__global__ void prep_k_kernel(const float* __restrict__ kvup, const float* __restrict__ kvd,
                              const float* __restrict__ fc, const float* __restrict__ fs,
                              short* __restrict__ kb, int n) {
  int idx = blockIdx.x * 256 + threadIdx.x;
  if (idx >= n) return;
  int i2 = idx % 96; int tmp = idx / 96;
  int h = tmp & 15; tmp >>= 4;
  int s = tmp & 2047; int b = tmp >> 11;
  int d0 = 2 * i2;
  float v0, v1;
  if (d0 < 128) {
    const float* row = kvup + ((size_t)(b * 2048 + s)) * 4096 + h * 256;
    v0 = row[d0]; v1 = row[d0 + 1];
  } else {
    int i = i2 - 64;
    const float* kr = kvd + ((size_t)(b * 2048 + s)) * 640;
    float c = fc[s * 32 + i], sn = fs[s * 32 + i];
    float x0 = kr[2 * i], x1 = kr[2 * i + 1];
    v0 = x0 * c - x1 * sn; v1 = x0 * sn + x1 * c;
  }
  uint32_t pk = (uint32_t)f2b(v0) | ((uint32_t)f2b(v1) << 16);
  *(uint32_t*)(kb + (((size_t)(b * 16 + h) * 2048 + s) * 192 + d0)) = pk;
}

// ---------------- prep_v: transpose V slice -> (B,H,128,S) bf16 --------------
__global__ __launch_bounds__(256) void prep_v_kernel(const float* __restrict__ kvup,
                                                     short* __restrict__ vT) {
  int bid = blockIdx.x;
  int st = bid & 31, dt = (bid >> 5) & 1, h = (bid >> 6) & 15, b = bid >> 10;
  __shared__ __align__(16) short tile[64][72];  // [d][s]
  int t = threadIdx.x;
  int c4 = (t & 15) * 4;
  const float* src = kvup + ((size_t)(b * 2048 + st * 64)) * 4096 + h * 256 + 128 + dt * 64;
#pragma unroll
  for (int it = 0; it < 4; ++it) {
    int sr = (t >> 4) + it * 16;
    float4 v = *(const float4*)(src + (size_t)sr * 4096 + c4);
    tile[c4 + 0][sr] = (short)f2b(v.x);
    tile[c4 + 1][sr] = (short)f2b(v.y);
    tile[c4 + 2][sr] = (short)f2b(v.z);
    tile[c4 + 3][sr] = (short)f2b(v.w);
  }
  __syncthreads();
  short* dst = vT + ((size_t)((b * 16 + h) * 128 + dt * 64)) * 2048 + st * 64;
#pragma unroll
  for (int it = 0; it < 4; ++it) {
    int dr = (t >> 4) + it * 16;
    short4 o;
    o.x = tile[dr][(t & 15) * 4 + 0];
    o.y = tile[dr][(t & 15) * 4 + 1];
    o.z = tile[dr][(t & 15) * 4 + 2];
    o.w = tile[dr][(t & 15) * 4 + 3];
    *(short4*)(dst + (size_t)dr * 2048 + (t & 15) * 4) = o;
  }
}

// ---------------- flash attention -------------------------------------------
// grid (32 qtiles, 32 bh). 4 waves x 16 q-rows. KT=32. Online softmax in
// MFMA D-layout; P -> A-frag layout via per-wave LDS round-trip.
__global__ __launch_bounds__(256) void attn_kernel(
    const short* __restrict__ qb, const short* __restrict__ kb,
    const short* __restrict__ vtb, short* __restrict__ ob) {
  __shared__ __align__(16) short Ks[32 * 192];
  __shared__ __align__(16) short Vs[128 * 32];
  __shared__ __align__(16) short Ps[4][512];
  int qt = blockIdx.x, bh = blockIdx.y;
  int b = bh >> 4, h = bh & 15;
  int q0 = qt * 64;
  int t = threadIdx.x, lane = t & 63, w = t >> 6;
  int l15 = lane & 15, l4 = lane >> 4;

  const short* Qbase = qb + ((size_t)bh * 2048 + q0 + w * 16) * 192;
  bf16x8 qf[6];
#pragma unroll
  for (int kk = 0; kk < 6; ++kk)
    qf[kk] = *(const bf16x8*)(Qbase + (size_t)l15 * 192 + kk * 32 + l4 * 8);

  f32x4 oacc[8] = {};
  float m_i[4] = {-1e30f, -1e30f, -1e30f, -1e30f};
  float l_i[4] = {0.f, 0.f, 0.f, 0.f};

  const short* Kbh = kb + (size_t)bh * 2048 * 192;
  const short* Vbh = vtb + (size_t)bh * 128 * 2048;

  int kend = q0 + 64;
  for (int kt = 0; kt < kend; kt += 32) {
#pragma unroll
    for (int c = 0; c < 3; ++c) {
      int idx = t + 256 * c;
      int r = idx / 24, ch = idx - r * 24;
      *(bf16x8*)(Ks + r * 192 + ch * 8) =
          *(const bf16x8*)(Kbh + (size_t)(kt + r) * 192 + ch * 8);
    }
#pragma unroll
    for (int c = 0; c < 2; ++c) {
      int idx = t + 256 * c;
      int d = idx >> 2, cc = (idx & 3) * 8;
      *(bf16x8*)(Vs + d * 32 + cc) =
          *(const bf16x8*)(Vbh + (size_t)d * 2048 + kt + cc);
    }
    __syncthreads();

    f32x4 s0 = {}, s1 = {};
#pragma unroll
    for (int kk = 0; kk < 6; ++kk) {
      bf16x8 k0 = *(const bf16x8*)(Ks + l15 * 192 + kk * 32 + l4 * 8);
      bf16x8 k1 = *(const bf16x8*)(Ks + (16 + l15) * 192 + kk * 32 + l4 * 8);
      s0 = __builtin_amdgcn_mfma_f32_16x16x32_bf16(qf[kk], k0, s0, 0, 0, 0);
      s1 = __builtin_amdgcn_mfma_f32_16x16x32_bf16(qf[kk], k1, s1, 0, 0, 0);
    }
    int qrow = q0 + w * 16 + l4 * 4;
    int kc0 = kt + l15, kc1 = kt + 16 + l15;
#pragma unroll
    for (int r = 0; r < 4; ++r) {
      float sa = (kc0 <= qrow + r) ? s0[r] : -1e30f;
      float sb = (kc1 <= qrow + r) ? s1[r] : -1e30f;
      float tm = fmaxf(sa, sb);
#pragma unroll
      for (int off = 1; off < 16; off <<= 1) tm = fmaxf(tm, __shfl_xor(tm, off));
      float newm = fmaxf(m_i[r], tm);
      float alpha = __expf(m_i[r] - newm);
      float p0 = __expf(sa - newm);
      float p1 = __expf(sb - newm);
      float rs = p0 + p1;
#pragma unroll
      for (int off = 1; off < 16; off <<= 1) rs += __shfl_xor(rs, off);
      l_i[r] = l_i[r] * alpha + rs;
      m_i[r] = newm;
#pragma unroll
      for (int dt = 0; dt < 8; ++dt) oacc[dt][r] *= alpha;
      Ps[w][(l4 * 4 + r) * 32 + l15] = (short)f2b(p0);
      Ps[w][(l4 * 4 + r) * 32 + 16 + l15] = (short)f2b(p1);
    }
    bf16x8 pf = *(const bf16x8*)(&Ps[w][l15 * 32 + l4 * 8]);
#pragma unroll
    for (int dt = 0; dt < 8; ++dt) {
      bf16x8 vf = *(const bf16x8*)(Vs + (dt * 16 + l15) * 32 + l4 * 8);
      oacc[dt] = __builtin_amdgcn_mfma_f32_16x16x32_bf16(pf, vf, oacc[dt], 0, 0, 0);
    }
    __syncthreads();
  }
#pragma unroll
  for (int r = 0; r < 4; ++r) {
    float inv = 1.0f / l_i[r];
    int row = q0 + w * 16 + l4 * 4 + r;
    short* dst = ob + ((size_t)(b * 2048 + row)) * 2048 + h * 128;
#pragma unroll
    for (int dt = 0; dt < 8; ++dt)
      dst[dt * 16 + l15] = (short)f2b(oacc[dt][r] * inv);
  }
}

// ---------------------------------------------------------------------------
extern "C" void kernel_launch(void* const* d_in, const int* in_sizes, int n_in,
                              void* d_out, int out_size, void* d_ws, size_t ws_size,
                              hipStream_t stream) {
  const float* x    = (const float*)d_in[0];
  const float* fcos = (const float*)d_in[1];
  const float* fsin = (const float*)d_in[2];
  const float* Wqd  = (const float*)d_in[3];
  const float* qnw  = (const float*)d_in[4];
  const float* Wqu  = (const float*)d_in[5];
  const float* Wkvd = (const float*)d_in[6];
  const float* kvnw = (const float*)d_in[7];
  const float* Wkvu = (const float*)d_in[8];
  const float* Wo   = (const float*)d_in[9];
  const float* bo   = (const float*)d_in[10];
  float* out = (float*)d_out;
  char* ws = (char*)d_ws;

  // workspace layout (bytes); reuse: q_b over x_bf/w_qd/w_qu, k_b/vT over qf32,
  // o_bf over qdown. Total ~218 MB.
  short* x_bf  = (short*)(ws + 0);           // 4096x2048 bf16
  short* w_qd  = (short*)(ws + 16777216);    // 1536x2048
  short* w_qu  = (short*)(ws + 23068672);    // 3072x1536
  short* w_kvd = (short*)(ws + 32505856);    // 640x2048 (padded)
  short* w_kvu = (short*)(ws + 35127296);    // 4096x512
  short* w_o   = (short*)(ws + 39321600);    // 2048x2048
  float* qdown = (float*)(ws + 47710208);    // 4096x1536 f32
  short* qn    = (short*)(ws + 72876032);    // 4096x1536 bf16
  float* qf32  = (float*)(ws + 85458944);    // 4096x3072 f32
  float* kv    = (float*)(ws + 135790592);   // 4096x640 f32
  short* ckvn  = (short*)(ws + 146276352);   // 4096x512 bf16
  float* kvup  = (float*)(ws + 150470656);   // 4096x4096 f32
  short* q_b   = (short*)(ws + 0);           // (B,H,S,192) bf16
  short* k_b   = (short*)(ws + 85458944);    // (B,H,S,192) bf16
  short* vT    = (short*)(ws + 110624768);   // (B,H,128,S) bf16
  short* o_bf  = (short*)(ws + 47710208);    // (B,S,2048) bf16

  // 1. conversions
  f2bf_kernel<<<8192, 256, 0, stream>>>(x, x_bf, 2097152);
  f2bf_kernel<<<3072, 256, 0, stream>>>(Wqd, w_qd, 786432);
  f2bf_kernel<<<4608, 256, 0, stream>>>(Wqu, w_qu, 1179648);
  f2bf_pad_kernel<<<1280, 256, 0, stream>>>(Wkvd, w_kvd, 327680, 512, 576);
  f2bf_kernel<<<2048, 256, 0, stream>>>(Wkvu, w_kvu, 524288);
  f2bf_kernel<<<4096, 256, 0, stream>>>(Wo, w_o, 1048576);

  // 2. q path
  gemm_bt_kernel<<<dim3(12, 32), 256, 0, stream>>>(x_bf, w_qd, qdown, nullptr, 2048, 1536);
  rmsnorm_kernel<<<4096, 256, 0, stream>>>(qdown, qnw, qn, 1536, 1536);
  gemm_bt_kernel<<<dim3(24, 32), 256, 0, stream>>>(qn, w_qu, qf32, nullptr, 1536, 3072);

  // 3. kv path
  gemm_bt_kernel<<<dim3(5, 32), 256, 0, stream>>>(x_bf, w_kvd, kv, nullptr, 2048, 640);
  rmsnorm_kernel<<<4096, 256, 0, stream>>>(kv + 64, kvnw, ckvn, 512, 640);
  gemm_bt_kernel<<<dim3(32, 32), 256, 0, stream>>>(ckvn, w_kvu, kvup, nullptr, 512, 4096);

  // 4. attention input prep (rope + repack + V transpose)
  prep_q_kernel<<<24576, 256, 0, stream>>>(qf32, fcos, fsin, q_b, 6291456);
  prep_k_kernel<<<24576, 256, 0, stream>>>(kvup, kv, fcos, fsin, k_b, 6291456);
  prep_v_kernel<<<2048, 256, 0, stream>>>(kvup, vT);

  // 5. attention
  attn_kernel<<<dim3(32, 32), 256, 0, stream>>>(q_b, k_b, vT, o_bf);

  // 6. output projection
  gemm_bt_kernel<<<dim3(16, 32), 256, 0, stream>>>(o_bf, w_o, out, bo, 2048, 2048);
}

// Round 2
// 459.387 us; speedup vs baseline: 1.3872x; 1.3872x over previous
//
#include <hip/hip_runtime.h>
#include <stdint.h>

// ---------------------------------------------------------------------------
// MLA forward on MI355X. Round 1:
//  - GEMM: global_load_lds width-16 staging (m97 structure), 128x128 tile.
//  - Attn: KT=64, padded LDS (bank-conflict fix), paired causal q-tiles.
// ---------------------------------------------------------------------------

typedef short bf16x8 __attribute__((ext_vector_type(8)));
typedef float f32x4  __attribute__((ext_vector_type(4)));
typedef unsigned int u32;

#define RMS_EPS 1.1920929e-07f

__device__ __forceinline__ unsigned short f2b(float f) {
  union { float f; uint32_t u; } c; c.f = f;
  uint32_t u = c.u;
  return (unsigned short)((u + 0x7FFFu + ((u >> 16) & 1u)) >> 16);
}

__device__ __forceinline__ void gld16(const short* g, short* l) {
  __builtin_amdgcn_global_load_lds(
      (const __attribute__((address_space(1))) u32*)g,
      (__attribute__((address_space(3))) u32*)l, 16, 0, 0);
}

// ---------------- fp32 -> bf16 conversion ----------------
__global__ void f2bf_kernel(const float* __restrict__ in, short* __restrict__ out, int n4) {
  int i = blockIdx.x * 256 + threadIdx.x;
  if (i >= n4) return;
  float4 v = ((const float4*)in)[i];
  union { ushort4 s; uint2 u; } o;
  o.s.x = f2b(v.x); o.s.y = f2b(v.y); o.s.z = f2b(v.z); o.s.w = f2b(v.w);
  ((uint2*)out)[i] = o.u;
}

__global__ void f2bf_pad_kernel(const float* __restrict__ in, short* __restrict__ out,
                                int n4, int cols4, int src_rows) {
  int i = blockIdx.x * 256 + threadIdx.x;
  if (i >= n4) return;
  int row = i / cols4;
  ushort4 s = {0, 0, 0, 0};
  if (row < src_rows) {
    float4 v = ((const float4*)in)[i];
    s.x = f2b(v.x); s.y = f2b(v.y); s.z = f2b(v.z); s.w = f2b(v.w);
  }
  union { ushort4 ss; uint2 u; } o; o.ss = s;
  ((uint2*)out)[i] = o.u;
}

// ---------------- GEMM: C[M,N]f32 = A[M,K]bf16 @ Bt[N,K]bf16^T (+bias) -------
// 128x128 tile, 4 waves (2x2), global_load_lds 16B staging, 16x16x32 MFMA.
__global__ __launch_bounds__(256) void gemm_bt_kernel(
    const short* __restrict__ A, const short* __restrict__ Bt,
    float* __restrict__ C, const float* __restrict__ bias,
    int K, int ldc) {
  __shared__ __align__(16) short As[128 * 32];
  __shared__ __align__(16) short Bs[128 * 32];
  int row0 = blockIdx.y * 128, col0 = blockIdx.x * 128;
  int t = threadIdx.x, lane = t & 63, w = t >> 6;
  int wm = w >> 1, wn = w & 1;
  int l15 = lane & 15, l4 = lane >> 4;
  f32x4 acc[4][4] = {};

  // staging: lane l of wave-call blk covers row blk*16 + (l>>2), col (l&3)*8;
  // LDS linear offset = blk*1024 + l*16 bytes (matches HW base + lane*16).
  int srow = lane >> 2, scol = (lane & 3) * 8;
  const short* Ag = A + (size_t)(row0 + srow) * K + scol;
  const short* Bg = Bt + (size_t)(col0 + srow) * K + scol;

  for (int kt = 0; kt < K; kt += 32) {
#pragma unroll
    for (int c = 0; c < 2; ++c) {
      int blk = w * 2 + c;  // wave-uniform 0..7
      gld16(Ag + (size_t)(blk * 16) * K + kt, As + blk * 512);
      gld16(Bg + (size_t)(blk * 16) * K + kt, Bs + blk * 512);
    }
    __syncthreads();
    bf16x8 af[4], bfr[4];
#pragma unroll
    for (int i = 0; i < 4; ++i) {
      af[i]  = *(const bf16x8*)(As + (wm * 64 + i * 16 + l15) * 32 + l4 * 8);
      bfr[i] = *(const bf16x8*)(Bs + (wn * 64 + i * 16 + l15) * 32 + l4 * 8);
    }
#pragma unroll
    for (int i = 0; i < 4; ++i)
#pragma unroll
      for (int j = 0; j < 4; ++j)
        acc[i][j] = __builtin_amdgcn_mfma_f32_16x16x32_bf16(af[i], bfr[j], acc[i][j], 0, 0, 0);
    __syncthreads();
  }
#pragma unroll
  for (int j = 0; j < 4; ++j) {
    int col = col0 + wn * 64 + j * 16 + l15;
    float bv = bias ? bias[col] : 0.0f;
#pragma unroll
    for (int i = 0; i < 4; ++i) {
      int row = row0 + wm * 64 + i * 16 + l4 * 4;
      float* dst = C + (size_t)row * ldc + col;
#pragma unroll
      for (int r = 0; r < 4; ++r) dst[(size_t)r * ldc] = acc[i][j][r] + bv;
    }
  }
}

// ---------------- RMSNorm (fp32 in, bf16 out) ----------------
__global__ __launch_bounds__(256) void rmsnorm_kernel(
    const float* __restrict__ in, const float* __restrict__ wgt,
    short* __restrict__ out, int W, int ld_in) {
  int row = blockIdx.x, t = threadIdx.x;
  const float* x = in + (size_t)row * ld_in;
  float ss = 0.f;
  for (int i = t; i < W; i += 256) { float v = x[i]; ss += v * v; }
#pragma unroll
  for (int off = 32; off > 0; off >>= 1) ss += __shfl_down(ss, off);
  __shared__ float red[4];
  if ((t & 63) == 0) red[t >> 6] = ss;
  __syncthreads();
  ss = red[0] + red[1] + red[2] + red[3];
  float rs = rsqrtf(ss / (float)W + RMS_EPS);
  for (int i = t; i < W; i += 256)
    out[(size_t)row * W + i] = (short)f2b(x[i] * rs * wgt[i]);
}

// ---------------- prep_q: rope + scale, (B,S,H,192)f32 -> (B,H,S,192)bf16 ----
__global__ void prep_q_kernel(const float* __restrict__ q, const float* __restrict__ fc,
                              const float* __restrict__ fs, short* __restrict__ qb, int n) {
  int idx = blockIdx.x * 256 + threadIdx.x;
  if (idx >= n) return;
  int i2 = idx % 96; int tmp = idx / 96;
  int h = tmp & 15; tmp >>= 4;
  int s = tmp & 2047; int b = tmp >> 11;
  const float* row = q + ((size_t)(b * 2048 + s)) * 3072 + h * 192;
  const float scale = 0.07216878364870323f;  // 1/sqrt(192)
  int d0 = 2 * i2;
  float v0, v1;
  if (d0 < 128) { v0 = row[d0]; v1 = row[d0 + 1]; }
  else {
    int i = i2 - 64;
    float c = fc[s * 32 + i], sn = fs[s * 32 + i];
    float x0 = row[d0], x1 = row[d0 + 1];
    v0 = x0 * c - x1 * sn; v1 = x0 * sn + x1 * c;
  }
  v0 *= scale; v1 *= scale;
  uint32_t pk = (uint32_t)f2b(v0) | ((uint32_t)f2b(v1) << 16);
  *(uint32_t*)(qb + (((size_t)(b * 16 + h) * 2048 + s) * 192 + d0)) = pk;
}

// ---------------- prep_k ----------------
__global__ void prep_k_kernel(const float* __restrict__ kvup, const float* __restrict__ kvd,
                              const float* __restrict__ fc, const float* __restrict__ fs,
                              short* __restrict__ kb, int n) {
  int idx = blockIdx.x * 256 + threadIdx.x;
  if (idx >= n) return;
  int i2 = idx % 96; int tmp = idx / 96;
  int h = tmp & 15; tmp >>= 4;
  int s = tmp & 2047; int b = tmp >> 11;
  int d0 = 2 * i2;
  float v0, v1;
  if (d0 < 128) {
    const float* row = kvup + ((size_t)(b * 2048 + s)) * 4096 + h * 256;
    v0 = row[d0]; v1 = row[d0 + 1];
  } else {
    int i = i2 - 64;
    const float* kr = kvd + ((size_t)(b * 2048 + s)) * 640;
    float c = fc[s * 32 + i], sn = fs[s * 32 + i];
    float x0 = kr[2 * i], x1 = kr[2 * i + 1];
    v0 = x0 * c - x1 * sn; v1 = x0 * sn + x1 * c;
  }
  uint32_t pk = (uint32_t)f2b(v0) | ((uint32_t)f2b(v1) << 16);
  *(uint32_t*)(kb + (((size_t)(b * 16 + h) * 2048 + s) * 192 + d0)) = pk;
}

// ---------------- prep_v: transpose V slice -> (B,H,128,S) bf16 --------------
__global__ __launch_bounds__(256) void prep_v_kernel(const float* __restrict__ kvup,
                                                     short* __restrict__ vT) {
  int bid = blockIdx.x;
  int st = bid & 31, dt = (bid >> 5) & 1, h = (bid >> 6) & 15, b = bid >> 10;
  __shared__ __align__(16) short tile[64][72];
  int t = threadIdx.x;
  int c4 = (t & 15) * 4;
  const float* src = kvup + ((size_t)(b * 2048 + st * 64)) * 4096 + h * 256 + 128 + dt * 64;
#pragma unroll
  for (int it = 0; it < 4; ++it) {
    int sr = (t >> 4) + it * 16;
    float4 v = *(const float4*)(src + (size_t)sr * 4096 + c4);
    tile[c4 + 0][sr] = (short)f2b(v.x);
    tile[c4 + 1][sr] = (short)f2b(v.y);
    tile[c4 + 2][sr] = (short)f2b(v.z);
    tile[c4 + 3][sr] = (short)f2b(v.w);
  }
  __syncthreads();
  short* dst = vT + ((size_t)((b * 16 + h) * 128 + dt * 64)) * 2048 + st * 64;
#pragma unroll
  for (int it = 0; it < 4; ++it) {
    int dr = (t >> 4) + it * 16;
    short4 o;
    o.x = tile[dr][(t & 15) * 4 + 0];
    o.y = tile[dr][(t & 15) * 4 + 1];
    o.z = tile[dr][(t & 15) * 4 + 2];
    o.w = tile[dr][(t & 15) * 4 + 3];
    *(short4*)(dst + (size_t)dr * 2048 + (t & 15) * 4) = o;
  }
}

// ---------------- flash attention -------------------------------------------
// grid (16, 32): block does q-tiles {x, 31-x} (33 K-iters each, balanced).
// 4 waves x 16 q-rows, KT=64, padded LDS (row+8 shorts) kills bank conflicts.
__global__ __launch_bounds__(256) void attn_kernel(
    const short* __restrict__ qb, const short* __restrict__ kb,
    const short* __restrict__ vtb, short* __restrict__ ob) {
  __shared__ __align__(16) short Ks[64 * 200];
  __shared__ __align__(16) short Vs[128 * 72];
  __shared__ __align__(16) short Ps[4][16 * 72];
  int bh = blockIdx.y;
  int b = bh >> 4, h = bh & 15;
  int t = threadIdx.x, lane = t & 63, w = t >> 6;
  int l15 = lane & 15, l4 = lane >> 4;
  const short* Kbh = kb + (size_t)bh * 2048 * 192;
  const short* Vbh = vtb + (size_t)bh * 128 * 2048;

  for (int half = 0; half < 2; ++half) {
    int qt = half ? (31 - (int)blockIdx.x) : (int)blockIdx.x;
    int q0 = qt * 64;
    const short* Qbase = qb + ((size_t)bh * 2048 + q0 + w * 16) * 192;
    bf16x8 qf[6];
#pragma unroll
    for (int kk = 0; kk < 6; ++kk)
      qf[kk] = *(const bf16x8*)(Qbase + (size_t)l15 * 192 + kk * 32 + l4 * 8);
    f32x4 oacc[8] = {};
    float m_i[4] = {-1e30f, -1e30f, -1e30f, -1e30f};
    float l_i[4] = {0.f, 0.f, 0.f, 0.f};
    int kend = q0 + 64;

    for (int kt = 0; kt < kend; kt += 64) {
#pragma unroll
      for (int c = 0; c < 6; ++c) {
        int idx = t + 256 * c;
        int r = idx / 24, ch = idx - r * 24;
        *(bf16x8*)(Ks + r * 200 + ch * 8) =
            *(const bf16x8*)(Kbh + (size_t)(kt + r) * 192 + ch * 8);
      }
#pragma unroll
      for (int c = 0; c < 4; ++c) {
        int idx = t + 256 * c;
        int d = idx >> 3, cc = (idx & 7) * 8;
        *(bf16x8*)(Vs + d * 72 + cc) =
            *(const bf16x8*)(Vbh + (size_t)d * 2048 + kt + cc);
      }
      __syncthreads();

      f32x4 s[4] = {};
#pragma unroll
      for (int kk = 0; kk < 6; ++kk) {
#pragma unroll
        for (int c = 0; c < 4; ++c) {
          bf16x8 kf = *(const bf16x8*)(Ks + (c * 16 + l15) * 200 + kk * 32 + l4 * 8);
          s[c] = __builtin_amdgcn_mfma_f32_16x16x32_bf16(qf[kk], kf, s[c], 0, 0, 0);
        }
      }
      int qrow = q0 + w * 16 + l4 * 4;
#pragma unroll
      for (int r = 0; r < 4; ++r) {
        float sv[4];
#pragma unroll
        for (int c = 0; c < 4; ++c) {
          int col = kt + c * 16 + l15;
          sv[c] = (col <= qrow + r) ? s[c][r] : -1e30f;
        }
        float tm = fmaxf(fmaxf(sv[0], sv[1]), fmaxf(sv[2], sv[3]));
#pragma unroll
        for (int off = 1; off < 16; off <<= 1) tm = fmaxf(tm, __shfl_xor(tm, off));
        float newm = fmaxf(m_i[r], tm);
        float alpha = __expf(m_i[r] - newm);
        float rs = 0.f;
#pragma unroll
        for (int c = 0; c < 4; ++c) {
          float p = __expf(sv[c] - newm);
          sv[c] = p; rs += p;
        }
#pragma unroll
        for (int off = 1; off < 16; off <<= 1) rs += __shfl_xor(rs, off);
        l_i[r] = l_i[r] * alpha + rs;
        m_i[r] = newm;
#pragma unroll
        for (int dt = 0; dt < 8; ++dt) oacc[dt][r] *= alpha;
        short* prow = &Ps[w][(l4 * 4 + r) * 72];
#pragma unroll
        for (int c = 0; c < 4; ++c) prow[c * 16 + l15] = (short)f2b(sv[c]);
      }
      bf16x8 pf0 = *(const bf16x8*)(&Ps[w][l15 * 72 + l4 * 8]);
      bf16x8 pf1 = *(const bf16x8*)(&Ps[w][l15 * 72 + 32 + l4 * 8]);
#pragma unroll
      for (int dt = 0; dt < 8; ++dt) {
        bf16x8 vf0 = *(const bf16x8*)(Vs + (dt * 16 + l15) * 72 + l4 * 8);
        bf16x8 vf1 = *(const bf16x8*)(Vs + (dt * 16 + l15) * 72 + 32 + l4 * 8);
        oacc[dt] = __builtin_amdgcn_mfma_f32_16x16x32_bf16(pf0, vf0, oacc[dt], 0, 0, 0);
        oacc[dt] = __builtin_amdgcn_mfma_f32_16x16x32_bf16(pf1, vf1, oacc[dt], 0, 0, 0);
      }
      __syncthreads();
    }
#pragma unroll
    for (int r = 0; r < 4; ++r) {
      float inv = 1.0f / l_i[r];
      int row = q0 + w * 16 + l4 * 4 + r;
      short* dst = ob + ((size_t)(b * 2048 + row)) * 2048 + h * 128;
#pragma unroll
      for (int dt = 0; dt < 8; ++dt)
        dst[dt * 16 + l15] = (short)f2b(oacc[dt][r] * inv);
    }
  }
}

// ---------------------------------------------------------------------------
extern "C" void kernel_launch(void* const* d_in, const int* in_sizes, int n_in,
                              void* d_out, int out_size, void* d_ws, size_t ws_size,
                              hipStream_t stream) {
  const float* x    = (const float*)d_in[0];
  const float* fcos = (const float*)d_in[1];
  const float* fsin = (const float*)d_in[2];
  const float* Wqd  = (const float*)d_in[3];
  const float* qnw  = (const float*)d_in[4];
  const float* Wqu  = (const float*)d_in[5];
  const float* Wkvd = (const float*)d_in[6];
  const float* kvnw = (const float*)d_in[7];
  const float* Wkvu = (const float*)d_in[8];
  const float* Wo   = (const float*)d_in[9];
  const float* bo   = (const float*)d_in[10];
  float* out = (float*)d_out;
  char* ws = (char*)d_ws;

  short* x_bf  = (short*)(ws + 0);           // 4096x2048 bf16
  short* w_qd  = (short*)(ws + 16777216);    // 1536x2048
  short* w_qu  = (short*)(ws + 23068672);    // 3072x1536
  short* w_kvd = (short*)(ws + 32505856);    // 640x2048 (padded)
  short* w_kvu = (short*)(ws + 35127296);    // 4096x512
  short* w_o   = (short*)(ws + 39321600);    // 2048x2048
  float* qdown = (float*)(ws + 47710208);    // 4096x1536 f32
  short* qn    = (short*)(ws + 72876032);    // 4096x1536 bf16
  float* qf32  = (float*)(ws + 85458944);    // 4096x3072 f32
  float* kv    = (float*)(ws + 135790592);   // 4096x640 f32
  short* ckvn  = (short*)(ws + 146276352);   // 4096x512 bf16
  float* kvup  = (float*)(ws + 150470656);   // 4096x4096 f32
  short* q_b   = (short*)(ws + 0);           // (B,H,S,192) bf16
  short* k_b   = (short*)(ws + 85458944);    // (B,H,S,192) bf16
  short* vT    = (short*)(ws + 110624768);   // (B,H,128,S) bf16
  short* o_bf  = (short*)(ws + 47710208);    // (B,S,2048) bf16

  f2bf_kernel<<<8192, 256, 0, stream>>>(x, x_bf, 2097152);
  f2bf_kernel<<<3072, 256, 0, stream>>>(Wqd, w_qd, 786432);
  f2bf_kernel<<<4608, 256, 0, stream>>>(Wqu, w_qu, 1179648);
  f2bf_pad_kernel<<<1280, 256, 0, stream>>>(Wkvd, w_kvd, 327680, 512, 576);
  f2bf_kernel<<<2048, 256, 0, stream>>>(Wkvu, w_kvu, 524288);
  f2bf_kernel<<<4096, 256, 0, stream>>>(Wo, w_o, 1048576);

  gemm_bt_kernel<<<dim3(12, 32), 256, 0, stream>>>(x_bf, w_qd, qdown, nullptr, 2048, 1536);
  rmsnorm_kernel<<<4096, 256, 0, stream>>>(qdown, qnw, qn, 1536, 1536);
  gemm_bt_kernel<<<dim3(24, 32), 256, 0, stream>>>(qn, w_qu, qf32, nullptr, 1536, 3072);

  gemm_bt_kernel<<<dim3(5, 32), 256, 0, stream>>>(x_bf, w_kvd, kv, nullptr, 2048, 640);
  rmsnorm_kernel<<<4096, 256, 0, stream>>>(kv + 64, kvnw, ckvn, 512, 640);
  gemm_bt_kernel<<<dim3(32, 32), 256, 0, stream>>>(ckvn, w_kvu, kvup, nullptr, 512, 4096);

  prep_q_kernel<<<24576, 256, 0, stream>>>(qf32, fcos, fsin, q_b, 6291456);
  prep_k_kernel<<<24576, 256, 0, stream>>>(kvup, kv, fcos, fsin, k_b, 6291456);
  prep_v_kernel<<<2048, 256, 0, stream>>>(kvup, vT);

  attn_kernel<<<dim3(16, 32), 256, 0, stream>>>(q_b, k_b, vT, o_bf);

  gemm_bt_kernel<<<dim3(16, 32), 256, 0, stream>>>(o_bf, w_o, out, bo, 2048, 2048);
}